// Round 2
// baseline (1151.835 us; speedup 1.0000x reference)
//
#include <hip/hip_runtime.h>
#include <hip/hip_bf16.h>

// MoE: T=16384 tokens, H=1024, I=2048, E=8, K=2 (top-2, renormalized)
#define T_TOK 16384
#define H_DIM 1024
#define I_DIM 2048
#define E_NUM 8

typedef short short8 __attribute__((ext_vector_type(8)));
typedef float f32x4 __attribute__((ext_vector_type(4)));

__device__ __forceinline__ unsigned short f2bf(float f) {
  union { float f; unsigned u; } v; v.f = f;
  unsigned r = (v.u + 0x7FFFu + ((v.u >> 16) & 1u)) >> 16;
  return (unsigned short)r;
}

__device__ __forceinline__ void gload16(const void* g, void* l) {
  __builtin_amdgcn_global_load_lds(
      (const __attribute__((address_space(1))) unsigned int*)g,
      (__attribute__((address_space(3))) unsigned int*)l, 16, 0, 0);
}

// ---------------- convert x (fp32 -> bf16) ----------------
__global__ __launch_bounds__(256) void convert_x_kernel(
    const float* __restrict__ src, unsigned short* __restrict__ dst, int n4) {
  int i = blockIdx.x * 256 + threadIdx.x;
  int stride = gridDim.x * 256;
  for (; i < n4; i += stride) {
    float4 v = ((const float4*)src)[i];
    ushort4 o;
    o.x = f2bf(v.x); o.y = f2bf(v.y); o.z = f2bf(v.z); o.w = f2bf(v.w);
    ((ushort4*)dst)[i] = o;
  }
}

// ------- transpose+convert weights: src[e][K][N] fp32 -> dst[e][N][K] bf16 ----
// grid (E, K/32, N/32), block (32, 8)
__global__ __launch_bounds__(256) void transpose_convert(
    const float* __restrict__ src, unsigned short* __restrict__ dst, int K, int N) {
  __shared__ float t[32][33];
  const int e = blockIdx.x, kt = blockIdx.y, nt = blockIdx.z;
  const int tx = threadIdx.x, ty = threadIdx.y;
  const float* s = src + (size_t)e * K * N;
  unsigned short* d = dst + (size_t)e * N * K;
#pragma unroll
  for (int j = 0; j < 4; ++j)
    t[ty + j * 8][tx] = s[(size_t)(kt * 32 + ty + j * 8) * N + nt * 32 + tx];
  __syncthreads();
#pragma unroll
  for (int j = 0; j < 4; ++j)
    d[(size_t)(nt * 32 + ty + j * 8) * K + kt * 32 + tx] = f2bf(t[tx][ty + j * 8]);
}

// ---------------- router: top-2 of softmax(x @ gate_w), renormalized ---------
// grid T/4, block 256 (wave per token)
__global__ __launch_bounds__(256) void router_kernel(
    const float* __restrict__ x, const float* __restrict__ gw,
    int* __restrict__ list, float* __restrict__ pwv, int* __restrict__ cnt) {
  __shared__ float gwl[H_DIM * 9];  // padded stride 9 to dodge bank conflicts
  const int tid = threadIdx.x;
  for (int i = tid; i < H_DIM * E_NUM; i += 256)
    gwl[(i >> 3) * 9 + (i & 7)] = gw[i];
  __syncthreads();

  const int lane = tid & 63;
  const int wv = tid >> 6;
  const int t = blockIdx.x * 4 + wv;
  const float* xr = x + (size_t)t * H_DIM;

  float acc[8] = {0.f, 0.f, 0.f, 0.f, 0.f, 0.f, 0.f, 0.f};
#pragma unroll
  for (int i = 0; i < 16; ++i) {
    float xv = xr[i * 64 + lane];
    const float* g = &gwl[(i * 64 + lane) * 9];
#pragma unroll
    for (int e = 0; e < 8; ++e) acc[e] += xv * g[e];
  }
#pragma unroll
  for (int e = 0; e < 8; ++e) {
#pragma unroll
    for (int off = 32; off; off >>= 1) acc[e] += __shfl_xor(acc[e], off);
  }
  // top-2 by logits (softmax monotone); ties -> lower index (matches lax.top_k)
  int e1 = 0; float l1 = acc[0];
#pragma unroll
  for (int e = 1; e < 8; ++e) if (acc[e] > l1) { l1 = acc[e]; e1 = e; }
  int first_non = (e1 == 0) ? 1 : 0;
  int e2 = first_non; float l2 = acc[first_non];
#pragma unroll
  for (int e = 0; e < 8; ++e) {
    if (e == e1 || e == first_non) continue;
    if (acc[e] > l2) { l2 = acc[e]; e2 = e; }
  }
  float r = expf(l2 - l1);
  float w1 = 1.f / (1.f + r);
  float w2 = r / (1.f + r);
  if (lane == 0) {
    int s1 = atomicAdd(&cnt[e1], 1);
    list[e1 * T_TOK + s1] = 2 * t;
    pwv[2 * t] = w1;
    int s2 = atomicAdd(&cnt[e2], 1);
    list[e2 * T_TOK + s2] = 2 * t + 1;
    pwv[2 * t + 1] = w2;
  }
}

// ------- GEMM A: h = w * silu(x@Wg) * (x@Wu), grouped by expert -------------
// grid (E*128, I/128), block 256. Wt layouts are [e][n][k] bf16.
__global__ __launch_bounds__(256, 2) void gemm_gateup(
    const unsigned short* __restrict__ xb, const unsigned short* __restrict__ wgt,
    const unsigned short* __restrict__ wut, const int* __restrict__ list,
    const int* __restrict__ cnt, const float* __restrict__ pwv,
    unsigned short* __restrict__ hbuf) {
  __shared__ unsigned short As[128 * 32];
  __shared__ unsigned short Bg[128 * 32];
  __shared__ unsigned short Bu[128 * 32];
  __shared__ int rows_s[128];
  __shared__ float pws[128];

  const int tid = threadIdx.x;
  const int e = blockIdx.x >> 7;
  const int mt = blockIdx.x & 127;
  const int ce = cnt[e];
  if (mt * 128 >= ce) return;
  const int n0 = blockIdx.y * 128;

  if (tid < 128) {
    int idx = mt * 128 + tid;
    int pid = list[e * T_TOK + (idx < ce ? idx : 0)];
    rows_s[tid] = pid;
    pws[tid] = pwv[pid];
  }
  __syncthreads();

  int tokA[2];
#pragma unroll
  for (int j = 0; j < 2; ++j) tokA[j] = rows_s[(j * 256 + tid) >> 2] >> 1;

  const unsigned short* wg_base = wgt + ((size_t)e * I_DIM + n0) * H_DIM;
  const unsigned short* wu_base = wut + ((size_t)e * I_DIM + n0) * H_DIM;

  f32x4 zero = {0.f, 0.f, 0.f, 0.f};
  f32x4 accg[4][4], accu[4][4];
#pragma unroll
  for (int m = 0; m < 4; ++m)
#pragma unroll
    for (int n = 0; n < 4; ++n) { accg[m][n] = zero; accu[m][n] = zero; }

  const int lane = tid & 63;
  const int wv = tid >> 6;
  const int wr = (wv >> 1) * 64;
  const int wc = (wv & 1) * 64;
  const int lr = lane & 15;
  const int lk = (lane >> 4) * 8;

  for (int kt = 0; kt < H_DIM / 32; ++kt) {
    const int k0 = kt * 32;
#pragma unroll
    for (int j = 0; j < 2; ++j) {
      int slot = j * 256 + tid;
      gload16(xb + (size_t)tokA[j] * H_DIM + k0 + (slot & 3) * 8, &As[slot * 8]);
    }
#pragma unroll
    for (int j = 0; j < 2; ++j) {
      int slot = j * 256 + tid;
      gload16(wg_base + (size_t)(slot >> 2) * H_DIM + k0 + (slot & 3) * 8, &Bg[slot * 8]);
    }
#pragma unroll
    for (int j = 0; j < 2; ++j) {
      int slot = j * 256 + tid;
      gload16(wu_base + (size_t)(slot >> 2) * H_DIM + k0 + (slot & 3) * 8, &Bu[slot * 8]);
    }
    __syncthreads();
    short8 a[4], bg[4], bu[4];
#pragma unroll
    for (int m = 0; m < 4; ++m)
      a[m] = *(const short8*)&As[(wr + m * 16 + lr) * 32 + lk];
#pragma unroll
    for (int n = 0; n < 4; ++n) {
      bg[n] = *(const short8*)&Bg[(wc + n * 16 + lr) * 32 + lk];
      bu[n] = *(const short8*)&Bu[(wc + n * 16 + lr) * 32 + lk];
    }
#pragma unroll
    for (int m = 0; m < 4; ++m)
#pragma unroll
      for (int n = 0; n < 4; ++n) {
        accg[m][n] = __builtin_amdgcn_mfma_f32_16x16x32_bf16(a[m], bg[n], accg[m][n], 0, 0, 0);
        accu[m][n] = __builtin_amdgcn_mfma_f32_16x16x32_bf16(a[m], bu[n], accu[m][n], 0, 0, 0);
      }
    __syncthreads();
  }

  const int rr = (lane >> 4) * 4;
#pragma unroll
  for (int m = 0; m < 4; ++m) {
#pragma unroll
    for (int j = 0; j < 4; ++j) {
      int tr = wr + m * 16 + rr + j;
      if (mt * 128 + tr < ce) {
        int pid = rows_s[tr];
        float wgt_r = pws[tr];
        size_t rowb = (size_t)pid * I_DIM + n0 + wc;
#pragma unroll
        for (int n = 0; n < 4; ++n) {
          float g = accg[m][n][j];
          float u = accu[m][n][j];
          float hv = wgt_r * (g / (1.f + __expf(-g))) * u;
          hbuf[rowb + n * 16 + lr] = f2bf(hv);
        }
      }
    }
  }
}

// ---------------- GEMM B: out[tok] += h @ Wd, grouped by expert -------------
// grid (E*128, H/128), block 256
__global__ __launch_bounds__(256, 2) void gemm_down(
    const unsigned short* __restrict__ hbuf, const unsigned short* __restrict__ wdt,
    const int* __restrict__ list, const int* __restrict__ cnt,
    float* __restrict__ out) {
  __shared__ unsigned short As[128 * 32];
  __shared__ unsigned short Bs[128 * 32];
  __shared__ int rows_s[128];

  const int tid = threadIdx.x;
  const int e = blockIdx.x >> 7;
  const int mt = blockIdx.x & 127;
  const int ce = cnt[e];
  if (mt * 128 >= ce) return;
  const int n0 = blockIdx.y * 128;

  if (tid < 128) {
    int idx = mt * 128 + tid;
    rows_s[tid] = list[e * T_TOK + (idx < ce ? idx : 0)];
  }
  __syncthreads();

  int pidA[2];
#pragma unroll
  for (int j = 0; j < 2; ++j) pidA[j] = rows_s[(j * 256 + tid) >> 2];

  const unsigned short* wd_base = wdt + ((size_t)e * H_DIM + n0) * I_DIM;

  f32x4 zero = {0.f, 0.f, 0.f, 0.f};
  f32x4 acc[4][4];
#pragma unroll
  for (int m = 0; m < 4; ++m)
#pragma unroll
    for (int n = 0; n < 4; ++n) acc[m][n] = zero;

  const int lane = tid & 63;
  const int wv = tid >> 6;
  const int wr = (wv >> 1) * 64;
  const int wc = (wv & 1) * 64;
  const int lr = lane & 15;
  const int lk = (lane >> 4) * 8;

  for (int kt = 0; kt < I_DIM / 32; ++kt) {
    const int k0 = kt * 32;
#pragma unroll
    for (int j = 0; j < 2; ++j) {
      int slot = j * 256 + tid;
      gload16(hbuf + (size_t)pidA[j] * I_DIM + k0 + (slot & 3) * 8, &As[slot * 8]);
    }
#pragma unroll
    for (int j = 0; j < 2; ++j) {
      int slot = j * 256 + tid;
      gload16(wd_base + (size_t)(slot >> 2) * I_DIM + k0 + (slot & 3) * 8, &Bs[slot * 8]);
    }
    __syncthreads();
    short8 a[4], b[4];
#pragma unroll
    for (int m = 0; m < 4; ++m)
      a[m] = *(const short8*)&As[(wr + m * 16 + lr) * 32 + lk];
#pragma unroll
    for (int n = 0; n < 4; ++n)
      b[n] = *(const short8*)&Bs[(wc + n * 16 + lr) * 32 + lk];
#pragma unroll
    for (int m = 0; m < 4; ++m)
#pragma unroll
      for (int n = 0; n < 4; ++n)
        acc[m][n] = __builtin_amdgcn_mfma_f32_16x16x32_bf16(a[m], b[n], acc[m][n], 0, 0, 0);
    __syncthreads();
  }

  const int rr = (lane >> 4) * 4;
#pragma unroll
  for (int m = 0; m < 4; ++m) {
#pragma unroll
    for (int j = 0; j < 4; ++j) {
      int tr = wr + m * 16 + rr + j;
      if (mt * 128 + tr < ce) {
        int pid = rows_s[tr];
        float* orow = out + (size_t)(pid >> 1) * H_DIM + n0 + wc;
#pragma unroll
        for (int n = 0; n < 4; ++n)
          atomicAdd(&orow[n * 16 + lr], acc[m][n][j]);
      }
    }
  }
}

// ---------------- launch ----------------
extern "C" void kernel_launch(void* const* d_in, const int* in_sizes, int n_in,
                              void* d_out, int out_size, void* d_ws, size_t ws_size,
                              hipStream_t stream) {
  const float* x = (const float*)d_in[0];
  const float* gw = (const float*)d_in[1];
  const float* wgf = (const float*)d_in[2];
  const float* wuf = (const float*)d_in[3];
  const float* wdf = (const float*)d_in[4];
  float* out = (float*)d_out;

  // Workspace layout (bytes). wgt/wut live in d_out during phase 1 (their
  // combined size == out bytes exactly); d_out is re-zeroed before gemm_down.
  const size_t off_xb   = 0;                 // T*H bf16   = 33,554,432
  const size_t off_wdt  = 33554432;          // E*H*I bf16 = 33,554,432
  const size_t off_h    = 67108864;          // 2T*I bf16  = 134,217,728
  const size_t off_list = 201326592;         // E*T int    = 524,288
  const size_t off_pw   = 201850880;         // 2T float   = 131,072
  const size_t off_cnt  = 201981952;         // E int
  const size_t ws_needed = off_cnt + 64;     // 201,982,016 (~192.6 MiB)
  if (ws_size < ws_needed) return;  // leaves output poisoned/zero -> failure signal

  char* ws = (char*)d_ws;
  unsigned short* xb   = (unsigned short*)(ws + off_xb);
  unsigned short* wdt  = (unsigned short*)(ws + off_wdt);
  unsigned short* hbuf = (unsigned short*)(ws + off_h);
  int*   list = (int*)(ws + off_list);
  float* pwv  = (float*)(ws + off_pw);
  int*   cnt  = (int*)(ws + off_cnt);

  unsigned short* wgt = (unsigned short*)d_out;                       // 33.5 MB
  unsigned short* wut = (unsigned short*)d_out + (size_t)E_NUM * H_DIM * I_DIM;

  hipMemsetAsync(cnt, 0, E_NUM * sizeof(int), stream);

  convert_x_kernel<<<2048, 256, 0, stream>>>(x, xb, T_TOK * H_DIM / 4);
  transpose_convert<<<dim3(E_NUM, H_DIM / 32, I_DIM / 32), dim3(32, 8), 0, stream>>>(
      wgf, wgt, H_DIM, I_DIM);
  transpose_convert<<<dim3(E_NUM, H_DIM / 32, I_DIM / 32), dim3(32, 8), 0, stream>>>(
      wuf, wut, H_DIM, I_DIM);
  transpose_convert<<<dim3(E_NUM, I_DIM / 32, H_DIM / 32), dim3(32, 8), 0, stream>>>(
      wdf, wdt, I_DIM, H_DIM);
  router_kernel<<<T_TOK / 4, 256, 0, stream>>>(x, gw, list, pwv, cnt);

  gemm_gateup<<<dim3(E_NUM * 128, I_DIM / 128), 256, 0, stream>>>(
      xb, wgt, wut, list, cnt, pwv, hbuf);

  // d_out held wgt/wut until here; now becomes the real (zeroed) output.
  hipMemsetAsync(d_out, 0, (size_t)out_size * sizeof(float), stream);

  gemm_down<<<dim3(E_NUM * 128, H_DIM / 128), 256, 0, stream>>>(
      hbuf, wdt, list, cnt, out);
}